// Round 8
// baseline (782.054 us; speedup 1.0000x reference)
//
#include <hip/hip_runtime.h>
#include <cmath>

#define NLVL 16
#define NDENSE 5     // levels 0..4 dense (2.65 MB total) -> fused in final pass
#define TPB 256
#define NP 2         // points per khash thread

struct LevelCfg { float scale; unsigned offset; unsigned res; };
struct DCfg { LevelCfg lv[NDENSE]; };

// One hashed level per launch (4MB table stays L2-resident chip-wide).
// 2 points per thread: all paired gather loads issued before any FMA.
// Staged chunk-locally into d_out: slot s=L-5 of chunk c at
// out2[c*256 + s*16 + (pt&15)] (128B-aligned coalesced segments).
__global__ __launch_bounds__(TPB) void khash_kernel(
    const float* __restrict__ x,
    const float2* __restrict__ grid,   // pre-offset to this level's table
    float2* __restrict__ out2,
    float scale, unsigned hm_mask, unsigned slot)
{
  const unsigned P1 = 2654435761u, P2 = 805459861u;
  const unsigned base = blockIdx.x * (TPB * NP) + threadIdx.x;

  unsigned pts[NP], b0v[NP];
  unsigned restv[NP][4];
  float wx[NP][2], wy[NP][2], wz[NP][2];
  float4 q[NP][4];             // even-b0 path: aligned pair loads
  float2 oa[NP][4], ob[NP][4]; // odd-b0 path: two float2 loads

#pragma unroll
  for (int p = 0; p < NP; ++p) {
    const unsigned pt = base + (unsigned)p * TPB;
    pts[p] = pt;
    const float px = x[pt * 3u + 0u];
    const float py = x[pt * 3u + 1u];
    const float pz = x[pt * 3u + 2u];

    // contraction-free f32 chain — matches reference rounding exactly
    const float p0 = __fadd_rn(__fmul_rn(scale, px), 0.5f);
    const float p1 = __fadd_rn(__fmul_rn(scale, py), 0.5f);
    const float p2 = __fadd_rn(__fmul_rn(scale, pz), 0.5f);
    const float fl0 = floorf(p0), fl1 = floorf(p1), fl2 = floorf(p2);
    const float fr0 = __fsub_rn(p0, fl0);
    const float fr1 = __fsub_rn(p1, fl1);
    const float fr2 = __fsub_rn(p2, fl2);
    const unsigned b0 = (unsigned)fl0, b1 = (unsigned)fl1, b2 = (unsigned)fl2;
    b0v[p] = b0;

    const unsigned hy0 = b1 * P1, hy1 = hy0 + P1;
    const unsigned hz0 = b2 * P2, hz1 = hz0 + P2;
    restv[p][0] = hy0 ^ hz0; restv[p][1] = hy0 ^ hz1;   // j=(by<<1)|bz
    restv[p][2] = hy1 ^ hz0; restv[p][3] = hy1 ^ hz1;

    wx[p][0] = __fsub_rn(1.0f, fr0); wx[p][1] = fr0;
    wy[p][0] = __fsub_rn(1.0f, fr1); wy[p][1] = fr1;
    wz[p][0] = __fsub_rn(1.0f, fr2); wz[p][1] = fr2;
  }

  // issue ALL gather loads (both points) before consuming any
#pragma unroll
  for (int p = 0; p < NP; ++p) {
    const unsigned b0 = b0v[p];
    if ((b0 & 1u) == 0u) {
      const float4* __restrict__ g4 = (const float4*)grid;
#pragma unroll
      for (int j = 0; j < 4; ++j) {
        const unsigned i0 = (b0 ^ restv[p][j]) & hm_mask;
        q[p][j] = g4[i0 >> 1];
      }
    }
    if ((b0v[p] & 1u) != 0u) {
#pragma unroll
      for (int j = 0; j < 4; ++j) {
        const unsigned i0 = (b0v[p] ^ restv[p][j]) & hm_mask;
        const unsigned i1 = ((b0v[p] + 1u) ^ restv[p][j]) & hm_mask;
        oa[p][j] = grid[i0];
        ob[p][j] = grid[i1];
      }
    }
  }

#pragma unroll
  for (int p = 0; p < NP; ++p) {
    const unsigned b0 = b0v[p];
    const bool beven = (b0 & 1u) == 0u;
    float ax = 0.0f, ay = 0.0f;
#pragma unroll
    for (int j = 0; j < 4; ++j) {
      const unsigned i0 = (b0 ^ restv[p][j]) & hm_mask;
      const bool odd = (i0 & 1u) != 0u;
      const float2 qlo = make_float2(q[p][j].x, q[p][j].y);
      const float2 qhi = make_float2(q[p][j].z, q[p][j].w);
      const float2 v0 = beven ? (odd ? qhi : qlo) : oa[p][j];
      const float2 v1 = beven ? (odd ? qlo : qhi) : ob[p][j];
      const float w0 = __fmul_rn(__fmul_rn(wx[p][0], wy[p][j >> 1]), wz[p][j & 1]);
      const float w1 = __fmul_rn(__fmul_rn(wx[p][1], wy[p][j >> 1]), wz[p][j & 1]);
      ax = __fmaf_rn(v0.x, w0, ax);  ay = __fmaf_rn(v0.y, w0, ay);
      ax = __fmaf_rn(v1.x, w1, ax);  ay = __fmaf_rn(v1.y, w1, ay);
    }
    const unsigned pt = pts[p];
    out2[(pt >> 4) * 256u + slot * 16u + (pt & 15u)] = make_float2(ax, ay);
  }
}

// Final pass, task-per-lane: 16 lanes per point, 2 points per thread.
// 20 corner-pair gathers per point (5 lvls x 4 (by,bz)-pairs) spread over the
// 16 lanes: task A = (lvl = sl>>2, j = sl&3) for all lanes, task B = (lvl4,
// j = sl) for lanes sl<4. Every gather instr has 64 active lanes. Partial
// sums reduce over the 4 j-lanes via shfl_xor (bits 0-1 of tid stay within a
// (point,lvl) group). Dense results assemble via LDS; staged hashed values
// read per-lane as before. Barrier (vmcnt-drain) orders all reads before the
// aliasing final overwrite — both chunks owned by this block only.
__global__ __launch_bounds__(TPB) void kasm_kernel(
    const float* __restrict__ x,
    const float2* __restrict__ grid,
    float2* out2,                      // read + write alias (chunk-local)
    DCfg cfg)
{
  __shared__ float s_x[96];
  __shared__ LevelCfg s_cfg[NDENSE];
  __shared__ float s_fx[32][NDENSE];
  __shared__ float s_fy[32][NDENSE];
  const unsigned tid = threadIdx.x;
  const unsigned sl  = tid & 15u;      // sub-lane role within point
  const unsigned lp  = tid >> 4;       // point-slot 0..15
  const unsigned jA  = tid & 3u;       // task-A pair index
  const unsigned lvlA = sl >> 2;       // task-A level 0..3
  const unsigned chunk0 = blockIdx.x * 2u;
  const unsigned pt0 = chunk0 * 16u;

  if (tid < NDENSE) s_cfg[tid] = cfg.lv[tid];
  if (tid < 96u) s_x[tid] = x[pt0 * 3u + tid];
  __syncthreads();

  // setup: index of corner-pair base (bx=0; bx=1 is +1) and the two weights
  auto dense_pair = [&](unsigned pp, unsigned lvl, unsigned j,
                        unsigned &i0, float &w0, float &w1) {
    const LevelCfg c = s_cfg[lvl];
    const float px = s_x[pp * 3u + 0u];
    const float py = s_x[pp * 3u + 1u];
    const float pz = s_x[pp * 3u + 2u];
    const float p0 = __fadd_rn(__fmul_rn(c.scale, px), 0.5f);
    const float p1 = __fadd_rn(__fmul_rn(c.scale, py), 0.5f);
    const float p2 = __fadd_rn(__fmul_rn(c.scale, pz), 0.5f);
    const float fl0 = floorf(p0), fl1 = floorf(p1), fl2 = floorf(p2);
    const float fr0 = __fsub_rn(p0, fl0);
    const float fr1 = __fsub_rn(p1, fl1);
    const float fr2 = __fsub_rn(p2, fl2);
    const unsigned b0 = (unsigned)fl0, b1 = (unsigned)fl1, b2 = (unsigned)fl2;
    const unsigned r = c.res, r2 = r * r;
    const unsigned by = j >> 1, bz = j & 1u;
    i0 = b0 + b1 * r + b2 * r2 + c.offset + (by ? r : 0u) + (bz ? r2 : 0u);
    const float wyf = by ? fr1 : __fsub_rn(1.0f, fr1);
    const float wzf = bz ? fr2 : __fsub_rn(1.0f, fr2);
    const float wyz = __fmul_rn(wyf, wzf);
    w0 = __fmul_rn(__fsub_rn(1.0f, fr0), wyz);
    w1 = __fmul_rn(fr0, wyz);
  };

  const bool hasB = (sl < 4u);
  unsigned iA[2], iB[2];
  float w0A[2], w1A[2], w0B[2], w1B[2];
#pragma unroll
  for (int p = 0; p < 2; ++p) {
    const unsigned pp = (unsigned)p * 16u + lp;
    dense_pair(pp, lvlA, jA, iA[p], w0A[p], w1A[p]);
    if (hasB) dense_pair(pp, NDENSE - 1, sl, iB[p], w0B[p], w1B[p]);
  }

  // issue all dense pair-gathers (one unaligned 16B load each)
  float qA[2][4], qB[2][4];
#pragma unroll
  for (int p = 0; p < 2; ++p)
    __builtin_memcpy(&qA[p][0], grid + iA[p], 16);
  if (hasB) {
#pragma unroll
    for (int p = 0; p < 2; ++p)
      __builtin_memcpy(&qB[p][0], grid + iB[p], 16);
  }

  // staged hashed reads (lanes sl>=5) — overlap with FMA/shuffle work below
  float2 staged[2];
  staged[0] = make_float2(0.0f, 0.0f); staged[1] = staged[0];
  if (sl >= NDENSE) {
#pragma unroll
    for (int p = 0; p < 2; ++p)
      staged[p] = out2[(chunk0 + (unsigned)p) * 256u + (sl - NDENSE) * 16u + lp];
  }

#pragma unroll
  for (int p = 0; p < 2; ++p) {
    const unsigned pp = (unsigned)p * 16u + lp;
    // task A: one corner pair of (pp, lvlA); reduce over the 4 j-lanes
    float ax = __fmaf_rn(qA[p][2], w1A[p], __fmul_rn(qA[p][0], w0A[p]));
    float ay = __fmaf_rn(qA[p][3], w1A[p], __fmul_rn(qA[p][1], w0A[p]));
    ax = __fadd_rn(ax, __shfl_xor(ax, 1));
    ay = __fadd_rn(ay, __shfl_xor(ay, 1));
    ax = __fadd_rn(ax, __shfl_xor(ax, 2));
    ay = __fadd_rn(ay, __shfl_xor(ay, 2));
    if (jA == 0u) { s_fx[pp][lvlA] = ax; s_fy[pp][lvlA] = ay; }
    // task B: lvl4 pairs live on lanes sl<4; zero elsewhere, same reduce
    float bx = 0.0f, by = 0.0f;
    if (hasB) {
      bx = __fmaf_rn(qB[p][2], w1B[p], __fmul_rn(qB[p][0], w0B[p]));
      by = __fmaf_rn(qB[p][3], w1B[p], __fmul_rn(qB[p][1], w0B[p]));
    }
    bx = __fadd_rn(bx, __shfl_xor(bx, 1));
    by = __fadd_rn(by, __shfl_xor(by, 1));
    bx = __fadd_rn(bx, __shfl_xor(bx, 2));
    by = __fadd_rn(by, __shfl_xor(by, 2));
    if (sl == 0u) { s_fx[pp][NDENSE - 1] = bx; s_fy[pp][NDENSE - 1] = by; }
  }

  __syncthreads();   // dense results visible; all staged reads drained
#pragma unroll
  for (int p = 0; p < 2; ++p) {
    const unsigned pp = (unsigned)p * 16u + lp;
    float2 v;
    if (sl < NDENSE) v = make_float2(s_fx[pp][sl], s_fy[pp][sl]);
    else             v = staged[p];
    out2[(chunk0 + (unsigned)p) * 256u + tid] = v;  // = out[pt0+16p+lp][sl]
  }
}

extern "C" void kernel_launch(void* const* d_in, const int* in_sizes, int n_in,
                              void* d_out, int out_size, void* d_ws, size_t ws_size,
                              hipStream_t stream) {
  const float*  x    = (const float*)d_in[0];
  const float2* grid = (const float2*)d_in[1];
  float2*       out2 = (float2*)d_out;

  // Mirror reference _level_config() in double (same libm chain as CPython).
  const unsigned hashmap_size = 1u << 19;
  const double per_level_scale = exp(log(2048.0 * 1.0 / 16.0) / (NLVL - 1));
  const double b = log2(per_level_scale);
  float  scales[NLVL];
  unsigned offsets[NLVL], ress[NLVL];
  unsigned n_params = 0;
  for (int i = 0; i < NLVL; ++i) {
    const double scale = pow(2.0, (double)i * b) * 16.0 - 1.0;
    const int res = (int)ceil(scale) + 1;
    const double res3 = pow((double)res, 3.0);
    unsigned p = (unsigned)(ceil(res3 / 8.0) * 8.0);
    if (p > hashmap_size) p = hashmap_size;
    offsets[i] = n_params;
    scales[i]  = (float)scale;
    ress[i]    = (unsigned)res;
    n_params += p;
  }

  const unsigned n_points = (unsigned)(in_sizes[0] / 3);

  // 11 hashed passes, stream-serialized: one 4MB table L2-resident at a time.
  const unsigned nblk_h = n_points / (TPB * NP);
  for (int L = NDENSE; L < NLVL; ++L) {
    khash_kernel<<<nblk_h, TPB, 0, stream>>>(
        x, grid + offsets[L], out2, scales[L], hashmap_size - 1u,
        (unsigned)(L - NDENSE));
  }

  DCfg cfg;
  for (int i = 0; i < NDENSE; ++i) {
    cfg.lv[i].scale  = scales[i];
    cfg.lv[i].offset = offsets[i];
    cfg.lv[i].res    = ress[i];
  }
  kasm_kernel<<<n_points / 32u, TPB, 0, stream>>>(x, grid, out2, cfg);
}

// Round 9
// 758.040 us; speedup vs baseline: 1.0317x; 1.0317x over previous
//
#include <hip/hip_runtime.h>
#include <cmath>

#define NLVL 16
#define NDENSE 5     // levels 0..4 dense (2.65 MB total) -> fused in final pass
#define TPB 256
#define NP 2         // points per khash thread
#define PC 4         // chunks (16-pt groups) per kfinal block

struct LevelCfg { float scale; unsigned offset; unsigned res; };
struct DCfg { LevelCfg lv[NDENSE]; };

// float2 non-temporal helpers (clang builtin needs scalar/ext-vector type)
static __device__ inline void nt_store_f2(float2* p, float2 v) {
  unsigned long long u;
  __builtin_memcpy(&u, &v, 8);
  __builtin_nontemporal_store(u, (unsigned long long*)p);
}
static __device__ inline float2 nt_load_f2(const float2* p) {
  unsigned long long u = __builtin_nontemporal_load((const unsigned long long*)p);
  float2 v;
  __builtin_memcpy(&v, &u, 8);
  return v;
}

// One hashed level per launch (4MB table stays L2-resident chip-wide).
// 2 points per thread: all paired gather loads issued before any FMA.
// Staged chunk-locally into d_out (slot s=L-5 of chunk c at
// out2[c*256 + s*16 + (pt&15)]); staged store is NON-TEMPORAL (written once,
// read once much later -> don't evict the hashed table from L2).
__global__ __launch_bounds__(TPB) void khash_kernel(
    const float* __restrict__ x,
    const float2* __restrict__ grid,   // pre-offset to this level's table
    float2* __restrict__ out2,
    float scale, unsigned hm_mask, unsigned slot)
{
  const unsigned P1 = 2654435761u, P2 = 805459861u;
  const unsigned base = blockIdx.x * (TPB * NP) + threadIdx.x;

  unsigned pts[NP], b0v[NP];
  unsigned restv[NP][4];
  float wx[NP][2], wy[NP][2], wz[NP][2];
  float4 q[NP][4];             // even-b0 path: aligned pair loads
  float2 oa[NP][4], ob[NP][4]; // odd-b0 path: two float2 loads

#pragma unroll
  for (int p = 0; p < NP; ++p) {
    const unsigned pt = base + (unsigned)p * TPB;
    pts[p] = pt;
    const float px = x[pt * 3u + 0u];
    const float py = x[pt * 3u + 1u];
    const float pz = x[pt * 3u + 2u];

    // contraction-free f32 chain — matches reference rounding exactly
    const float p0 = __fadd_rn(__fmul_rn(scale, px), 0.5f);
    const float p1 = __fadd_rn(__fmul_rn(scale, py), 0.5f);
    const float p2 = __fadd_rn(__fmul_rn(scale, pz), 0.5f);
    const float fl0 = floorf(p0), fl1 = floorf(p1), fl2 = floorf(p2);
    const float fr0 = __fsub_rn(p0, fl0);
    const float fr1 = __fsub_rn(p1, fl1);
    const float fr2 = __fsub_rn(p2, fl2);
    const unsigned b0 = (unsigned)fl0, b1 = (unsigned)fl1, b2 = (unsigned)fl2;
    b0v[p] = b0;

    const unsigned hy0 = b1 * P1, hy1 = hy0 + P1;
    const unsigned hz0 = b2 * P2, hz1 = hz0 + P2;
    restv[p][0] = hy0 ^ hz0; restv[p][1] = hy0 ^ hz1;   // j=(by<<1)|bz
    restv[p][2] = hy1 ^ hz0; restv[p][3] = hy1 ^ hz1;

    wx[p][0] = __fsub_rn(1.0f, fr0); wx[p][1] = fr0;
    wy[p][0] = __fsub_rn(1.0f, fr1); wy[p][1] = fr1;
    wz[p][0] = __fsub_rn(1.0f, fr2); wz[p][1] = fr2;
  }

  // issue ALL gather loads (both points) before consuming any
#pragma unroll
  for (int p = 0; p < NP; ++p) {
    const unsigned b0 = b0v[p];
    if ((b0 & 1u) == 0u) {
      const float4* __restrict__ g4 = (const float4*)grid;
#pragma unroll
      for (int j = 0; j < 4; ++j) {
        const unsigned i0 = (b0 ^ restv[p][j]) & hm_mask;
        q[p][j] = g4[i0 >> 1];
      }
    }
    if ((b0v[p] & 1u) != 0u) {
#pragma unroll
      for (int j = 0; j < 4; ++j) {
        const unsigned i0 = (b0v[p] ^ restv[p][j]) & hm_mask;
        const unsigned i1 = ((b0v[p] + 1u) ^ restv[p][j]) & hm_mask;
        oa[p][j] = grid[i0];
        ob[p][j] = grid[i1];
      }
    }
  }

#pragma unroll
  for (int p = 0; p < NP; ++p) {
    const unsigned b0 = b0v[p];
    const bool beven = (b0 & 1u) == 0u;
    float ax = 0.0f, ay = 0.0f;
#pragma unroll
    for (int j = 0; j < 4; ++j) {
      const unsigned i0 = (b0 ^ restv[p][j]) & hm_mask;
      const bool odd = (i0 & 1u) != 0u;
      const float2 qlo = make_float2(q[p][j].x, q[p][j].y);
      const float2 qhi = make_float2(q[p][j].z, q[p][j].w);
      const float2 v0 = beven ? (odd ? qhi : qlo) : oa[p][j];
      const float2 v1 = beven ? (odd ? qlo : qhi) : ob[p][j];
      const float w0 = __fmul_rn(__fmul_rn(wx[p][0], wy[p][j >> 1]), wz[p][j & 1]);
      const float w1 = __fmul_rn(__fmul_rn(wx[p][1], wy[p][j >> 1]), wz[p][j & 1]);
      ax = __fmaf_rn(v0.x, w0, ax);  ay = __fmaf_rn(v0.y, w0, ay);
      ax = __fmaf_rn(v1.x, w1, ax);  ay = __fmaf_rn(v1.y, w1, ay);
    }
    const unsigned pt = pts[p];
    nt_store_f2(&out2[(pt >> 4) * 256u + slot * 16u + (pt & 15u)],
                make_float2(ax, ay));
  }
}

// Final pass, 16 lanes per point, 4 points per thread (PC=4 chunks/block),
// 2-deep ping-pong on dense pair-load buffers (2x outstanding loads/lane vs
// round-7). Dense corner-pair (i0,i0+1) is contiguous (dim0-stride 1) -> one
// unaligned 16B load per pair. Staged reads + final stores non-temporal
// (single-use streams; keep dense tables cached). __syncthreads() (vmcnt
// drain) orders staged reads before the aliasing overwrite; all 4 chunks are
// owned by this block only.
__global__ __launch_bounds__(TPB) void kfinal_kernel(
    const float* __restrict__ x,
    const float2* __restrict__ grid,
    float2* out2,                      // read + write alias (chunk-local)
    DCfg cfg)
{
  __shared__ float s_x[48 * PC];
  __shared__ LevelCfg s_cfg[NDENSE];
  const unsigned tid = threadIdx.x;
  const unsigned lvl = tid & 15u;
  const unsigned lp  = tid >> 4;
  const unsigned chunk0 = blockIdx.x * PC;
  const unsigned pt0 = chunk0 * 16u;

  // staged hashed results: issue FIRST (overlap entire dense computation)
  float2 staged[PC];
#pragma unroll
  for (int p = 0; p < PC; ++p) staged[p] = make_float2(0.0f, 0.0f);
  if (lvl >= NDENSE) {
#pragma unroll
    for (int p = 0; p < PC; ++p)
      staged[p] = nt_load_f2(
          &out2[(chunk0 + (unsigned)p) * 256u + (lvl - NDENSE) * 16u + lp]);
  }

  if (tid < NDENSE) s_cfg[tid] = cfg.lv[tid];
  if (tid < 48u * PC) s_x[tid] = x[pt0 * 3u + tid];
  __syncthreads();

  float ax[PC], ay[PC];
  if (lvl < NDENSE) {
    const LevelCfg c = s_cfg[lvl];
    const unsigned r = c.res, r2 = r * r;
    const unsigned doff[4] = { 0u, r2, r, r + r2 };  // j=(by<<1)|bz

    unsigned i0[PC][4];
    float w0[PC][4], w1[PC][4];
#pragma unroll
    for (int p = 0; p < PC; ++p) {
      const unsigned lpp = (unsigned)p * 16u + lp;
      const float px = s_x[lpp * 3u + 0u];
      const float py = s_x[lpp * 3u + 1u];
      const float pz = s_x[lpp * 3u + 2u];
      const float p0 = __fadd_rn(__fmul_rn(c.scale, px), 0.5f);
      const float p1 = __fadd_rn(__fmul_rn(c.scale, py), 0.5f);
      const float p2 = __fadd_rn(__fmul_rn(c.scale, pz), 0.5f);
      const float fl0 = floorf(p0), fl1 = floorf(p1), fl2 = floorf(p2);
      const float fr0 = __fsub_rn(p0, fl0);
      const float fr1 = __fsub_rn(p1, fl1);
      const float fr2 = __fsub_rn(p2, fl2);
      const unsigned b0 = (unsigned)fl0, b1 = (unsigned)fl1, b2 = (unsigned)fl2;
      const unsigned dbase = b0 + b1 * r + b2 * r2 + c.offset;
      const float wyv[2] = { __fsub_rn(1.0f, fr1), fr1 };
      const float wzv[2] = { __fsub_rn(1.0f, fr2), fr2 };
      const float wx0 = __fsub_rn(1.0f, fr0);
#pragma unroll
      for (int j = 0; j < 4; ++j) {
        i0[p][j] = dbase + doff[j];
        const float wyz = __fmul_rn(wyv[j >> 1], wzv[j & 1]);
        w0[p][j] = __fmul_rn(wx0, wyz);
        w1[p][j] = __fmul_rn(fr0, wyz);
      }
    }

    // 2-deep ping-pong: q[0] <- p0, q[1] <- p1; consume p, refill with p+2
    float q[2][4][4];
#pragma unroll
    for (int j = 0; j < 4; ++j) __builtin_memcpy(&q[0][j][0], grid + i0[0][j], 16);
#pragma unroll
    for (int j = 0; j < 4; ++j) __builtin_memcpy(&q[1][j][0], grid + i0[1][j], 16);

#pragma unroll
    for (int p = 0; p < PC; ++p) {
      const int buf = p & 1;
      float axx = 0.0f, ayy = 0.0f;
#pragma unroll
      for (int j = 0; j < 4; ++j) {
        axx = __fmaf_rn(q[buf][j][0], w0[p][j], axx);
        ayy = __fmaf_rn(q[buf][j][1], w0[p][j], ayy);
        axx = __fmaf_rn(q[buf][j][2], w1[p][j], axx);
        ayy = __fmaf_rn(q[buf][j][3], w1[p][j], ayy);
      }
      ax[p] = axx; ay[p] = ayy;
      if (p + 2 < PC) {
#pragma unroll
        for (int j = 0; j < 4; ++j)
          __builtin_memcpy(&q[buf][j][0], grid + i0[p + 2][j], 16);
      }
    }
  } else {
#pragma unroll
    for (int p = 0; p < PC; ++p) { ax[p] = staged[p].x; ay[p] = staged[p].y; }
  }

  __syncthreads();   // all staged reads complete before region overwrite
#pragma unroll
  for (int p = 0; p < PC; ++p)
    nt_store_f2(&out2[(chunk0 + (unsigned)p) * 256u + tid],
                make_float2(ax[p], ay[p]));   // = out[pt0+16p+lp][lvl]
}

extern "C" void kernel_launch(void* const* d_in, const int* in_sizes, int n_in,
                              void* d_out, int out_size, void* d_ws, size_t ws_size,
                              hipStream_t stream) {
  const float*  x    = (const float*)d_in[0];
  const float2* grid = (const float2*)d_in[1];
  float2*       out2 = (float2*)d_out;

  // Mirror reference _level_config() in double (same libm chain as CPython).
  const unsigned hashmap_size = 1u << 19;
  const double per_level_scale = exp(log(2048.0 * 1.0 / 16.0) / (NLVL - 1));
  const double b = log2(per_level_scale);
  float  scales[NLVL];
  unsigned offsets[NLVL], ress[NLVL];
  unsigned n_params = 0;
  for (int i = 0; i < NLVL; ++i) {
    const double scale = pow(2.0, (double)i * b) * 16.0 - 1.0;
    const int res = (int)ceil(scale) + 1;
    const double res3 = pow((double)res, 3.0);
    unsigned p = (unsigned)(ceil(res3 / 8.0) * 8.0);
    if (p > hashmap_size) p = hashmap_size;
    offsets[i] = n_params;
    scales[i]  = (float)scale;
    ress[i]    = (unsigned)res;
    n_params += p;
  }

  const unsigned n_points = (unsigned)(in_sizes[0] / 3);

  // 11 hashed passes, stream-serialized: one 4MB table L2-resident at a time.
  const unsigned nblk_h = n_points / (TPB * NP);
  for (int L = NDENSE; L < NLVL; ++L) {
    khash_kernel<<<nblk_h, TPB, 0, stream>>>(
        x, grid + offsets[L], out2, scales[L], hashmap_size - 1u,
        (unsigned)(L - NDENSE));
  }

  DCfg cfg;
  for (int i = 0; i < NDENSE; ++i) {
    cfg.lv[i].scale  = scales[i];
    cfg.lv[i].offset = offsets[i];
    cfg.lv[i].res    = ress[i];
  }
  kfinal_kernel<<<n_points / (16u * PC), TPB, 0, stream>>>(x, grid, out2, cfg);
}